// Round 9
// baseline (98.703 us; speedup 1.0000x reference)
//
#include <hip/hip_runtime.h>

// out[i, j] = x[i, j] * a[j];  x: [65536, 1024] f32, a: [1024] f32.
//
// ISOLATION EXPERIMENT (R9): identical structure to R8 (block-dense x4
// unroll, reg-hoisted scale, 32-bit indexing) but PLAIN stores instead of
// nontemporal. R4->R5's "nt stores help" conclusion changed two variables
// at once (loop shape + store policy); this isolates store policy.
//  - If FETCH_SIZE jumps ~131MB -> ~256MB and dur rises: nt's L3
//    protection confirmed -> revert to R8, declare roofline.
//  - If dur drops below 82us: nt was capping write throughput (bypassing
//    L2 aggregation); pursue store aux-bit variants.

#define XSIZE 1024
#define XSIZE4 (XSIZE / 4)   // 256 float4 column-quads

typedef float f4 __attribute__((ext_vector_type(4)));

__global__ __launch_bounds__(256) void ic_adjust_kernel(
    const float* __restrict__ x,
    const float* __restrict__ a,
    float* __restrict__ out,
    int n4) {
    const f4* __restrict__ x4 = reinterpret_cast<const f4*>(x);
    const f4* __restrict__ a4 = reinterpret_cast<const f4*>(a);
    f4* __restrict__ o4 = reinterpret_cast<f4*>(out);

    constexpr int B = 256;   // block size
    constexpr int U = 4;     // chunks per block per iteration
    const int start = U * blockIdx.x * B + threadIdx.x;
    const int stride = U * gridDim.x * B;

    // All U accesses have column-quad tid & 255 (offsets are multiples of
    // 256): one loop-invariant scale register.
    const f4 s = a4[threadIdx.x & (XSIZE4 - 1)];

    for (int i = start; i + (U - 1) * B < n4; i += stride) {
        f4 v0 = x4[i];            // four contiguous-1KiB wave loads in flight
        f4 v1 = x4[i + B];
        f4 v2 = x4[i + 2 * B];
        f4 v3 = x4[i + 3 * B];
        v0 *= s;
        v1 *= s;
        v2 *= s;
        v3 *= s;
        o4[i] = v0;               // PLAIN stores (the only change vs R8)
        o4[i + B] = v1;
        o4[i + 2 * B] = v2;
        o4[i + 3 * B] = v3;
    }
}

extern "C" void kernel_launch(void* const* d_in, const int* in_sizes, int n_in,
                              void* d_out, int out_size, void* d_ws, size_t ws_size,
                              hipStream_t stream) {
    const float* x = (const float*)d_in[0];
    const float* a = (const float*)d_in[1];
    float* out = (float*)d_out;

    const int n4 = out_size / 4;  // 16,777,216 float4s

    const int block = 256;
    int blocks_needed = (n4 + 4 * block - 1) / (4 * block);
    int grid = (blocks_needed < 2048) ? blocks_needed : 2048;

    ic_adjust_kernel<<<grid, block, 0, stream>>>(x, a, out, n4);
}

// Round 10
// 82.800 us; speedup vs baseline: 1.1921x; 1.1921x over previous
//
#include <hip/hip_runtime.h>

// out[i, j] = x[i, j] * a[j];  x: [65536, 1024] f32, a: [1024] f32.
//
// FINAL (= R8, reverted after the R9 store-policy A/B):
//  - Cached loads + NONTEMPORAL stores. Isolated A/B (R8 vs R9, identical
//    structure): nt stores 82.25us vs plain stores 98.70us. out's write
//    allocations were evicting x from the 256 MiB Infinity Cache; nt keeps
//    x ~50% L3-resident (FETCH 131 MB instead of 256 MB).
//  - nt loads regress (R3): they forfeit the L3 hits entirely.
//  - nt stores MUST be per-instruction contiguous (R6: lane-interleaved
//    stores -> +15% WRITE_SIZE amplification). Every access here is a
//    dense 1 KiB wave segment.
//  - Block-dense x4 unroll: each block owns four ADJACENT 4 KiB chunks
//    (thread handles i, i+256, i+512, i+768). x2->x4 was neutral => MLP
//    saturated; kept at 4.
//  - Grid 2048 x 256 = exactly full residency (8 blocks/CU x 256 CU).
//  - Offsets are multiples of 256 quads -> ONE loop-invariant scale
//    register; no LDS, no lgkmcnt in hot loop. 32-bit index math.
//
// Roofline: 512 MiB data motion / 82.25us = 6.23 TB/s = 99% of the 6.29
// TB/s measured copy ceiling for this 1:1 R:W streaming mix.

#define XSIZE 1024
#define XSIZE4 (XSIZE / 4)   // 256 float4 column-quads

typedef float f4 __attribute__((ext_vector_type(4)));

__global__ __launch_bounds__(256) void ic_adjust_kernel(
    const float* __restrict__ x,
    const float* __restrict__ a,
    float* __restrict__ out,
    int n4) {
    const f4* __restrict__ x4 = reinterpret_cast<const f4*>(x);
    const f4* __restrict__ a4 = reinterpret_cast<const f4*>(a);
    f4* __restrict__ o4 = reinterpret_cast<f4*>(out);

    constexpr int B = 256;   // block size
    constexpr int U = 4;     // chunks per block per iteration
    const int start = U * blockIdx.x * B + threadIdx.x;
    const int stride = U * gridDim.x * B;

    // All U accesses have column-quad tid & 255 (offsets are multiples of
    // 256): one loop-invariant scale register.
    const f4 s = a4[threadIdx.x & (XSIZE4 - 1)];

    for (int i = start; i + (U - 1) * B < n4; i += stride) {
        f4 v0 = x4[i];            // four contiguous-1KiB wave loads in flight
        f4 v1 = x4[i + B];
        f4 v2 = x4[i + 2 * B];
        f4 v3 = x4[i + 3 * B];
        v0 *= s;
        v1 *= s;
        v2 *= s;
        v3 *= s;
        __builtin_nontemporal_store(v0, &o4[i]);        // dense 1KiB segments
        __builtin_nontemporal_store(v1, &o4[i + B]);
        __builtin_nontemporal_store(v2, &o4[i + 2 * B]);
        __builtin_nontemporal_store(v3, &o4[i + 3 * B]);
    }
}

extern "C" void kernel_launch(void* const* d_in, const int* in_sizes, int n_in,
                              void* d_out, int out_size, void* d_ws, size_t ws_size,
                              hipStream_t stream) {
    const float* x = (const float*)d_in[0];
    const float* a = (const float*)d_in[1];
    float* out = (float*)d_out;

    const int n4 = out_size / 4;  // 16,777,216 float4s

    const int block = 256;
    int blocks_needed = (n4 + 4 * block - 1) / (4 * block);
    int grid = (blocks_needed < 2048) ? blocks_needed : 2048;

    ic_adjust_kernel<<<grid, block, 0, stream>>>(x, a, out, n4);
}